// Round 6
// baseline (343.247 us; speedup 1.0000x reference)
//
#include <hip/hip_runtime.h>

// ---------------------------------------------------------------------------
// SparseMultiHeadAttention (windowed, W=4) forward on MI355X / gfx950
// R6: zero-fill via block-role specialization inside the GEMM dispatches
//     (filler blocks co-resident with MFMA blocks; no vmcnt/barrier coupling),
//     XCD-aware tile mapping for GEMM L2 reuse.
//   x -> bf16                                  (xconv_k)
//   Wq/Wk/Wv/Wo -> bf16 transposed [N][K]      (wconv_k)
//   QKV = x@[Wq|Wk|Wv]+b, bf16 out             (gemm_qkv_k: 1536 GEMM + 512 filler blocks)
//   banded softmax, band-chunk writes, PV      (attn_k: + zero share)
//   out = attn@Wo + bo, fp32                   (gemm_out_k: 512 GEMM + 256 filler blocks)
// Weights chunk partition (16B chunks, 67,108,864 total):
//   [0, 37748736)          gemm_qkv_k fillers (512 blk x 256 thr x 288)
//   [37748736, 54525952)   gemm_out_k fillers (256 blk x 256 thr x 256)
//   [54525952, 67108864)   attn_k             (guarded 2 per thread)
// Zero writers skip band chunks [f0,f1] per row; attn_k writes those with
// band values merged. Disjoint -> order across kernels irrelevant.
// ---------------------------------------------------------------------------

typedef __attribute__((ext_vector_type(8))) short short8;
typedef __attribute__((ext_vector_type(4))) float f32x4;

#define B_    4
#define S_    2048
#define D_    1024
#define H_    16
#define HD_   64
#define WIN_  4
#define NROW  (B_ * S_)                           /* 8192 */
#define OUT0_ELEMS  ((size_t)B_ * S_ * D_)        /* 8388608 */
#define TOTAL_CH (67108864ull)
#define Z0_CH 37748736ull
#define Z1_CH 16777216ull
#define ZA_BASE (Z0_CH + Z1_CH)                   /* 54525952 */

__device__ __forceinline__ unsigned short f2bf(float f) {
  unsigned int u = __float_as_uint(f);
  u += 0x7fffu + ((u >> 16) & 1u);                // round-to-nearest-even
  return (unsigned short)(u >> 16);
}
__device__ __forceinline__ float bf2f(unsigned short u) {
  return __uint_as_float(((unsigned int)u) << 16);
}

// NT-store 16B of zeros at chunk g unless g is a band chunk of its row.
__device__ __forceinline__ void zstore(f32x4* __restrict__ woutv, size_t g) {
  int row = (int)(g >> 9);
  int f = (int)(g & 511);
  int s = row & (S_ - 1);
  int f0 = (s > WIN_) ? ((s - WIN_) >> 2) : 0;
  int hi = (s + WIN_ < S_ - 1) ? (s + WIN_) : (S_ - 1);
  int f1 = hi >> 2;
  if (f < f0 || f > f1) {
    f32x4 z = {0.f, 0.f, 0.f, 0.f};
    __builtin_nontemporal_store(z, woutv + g);
  }
}

// ---------------- fp32 -> bf16 elementwise (x) ------------------------------
__global__ __launch_bounds__(256) void xconv_k(const float* __restrict__ x,
                                               unsigned short* __restrict__ o) {
  int i = blockIdx.x * 256 + threadIdx.x;         // one float4 per thread
  float4 f = reinterpret_cast<const float4*>(x)[i];
  ushort4 u;
  u.x = f2bf(f.x); u.y = f2bf(f.y); u.z = f2bf(f.z); u.w = f2bf(f.w);
  reinterpret_cast<ushort4*>(o)[i] = u;
}

// ---------------- fp32 [K][N] -> bf16 transposed [N][K] (4 weight mats) -----
__global__ __launch_bounds__(256) void wconv_k(const float* __restrict__ W0,
                                               const float* __restrict__ W1,
                                               const float* __restrict__ W2,
                                               const float* __restrict__ W3,
                                               unsigned short* __restrict__ out) {
  __shared__ float t[32][33];
  const float* Ws[4] = {W0, W1, W2, W3};
  const float* W = Ws[blockIdx.z];
  unsigned short* o = out + (size_t)blockIdx.z * D_ * D_;
  int tx = threadIdx.x;                           // 0..31
  int ty = threadIdx.y;                           // 0..7
  int n0 = blockIdx.x * 32, k0 = blockIdx.y * 32;
#pragma unroll
  for (int i = 0; i < 4; ++i)
    t[ty + 8 * i][tx] = W[(size_t)(k0 + ty + 8 * i) * D_ + (n0 + tx)];
  __syncthreads();
#pragma unroll
  for (int i = 0; i < 4; ++i)
    o[(size_t)(n0 + ty + 8 * i) * D_ + (k0 + tx)] = f2bf(t[tx][ty + 8 * i]);
}

#define GLD16(g, l)                                                            \
  __builtin_amdgcn_global_load_lds(                                            \
      (const __attribute__((address_space(1))) unsigned int*)(g),              \
      (__attribute__((address_space(3))) unsigned int*)(l), 16, 0, 0)

// ---------------- fused QKV GEMM (M=8192, N=3072, K=1024), bf16 out --------
// 2048 blocks: g8=b>>3, o=b&7 (o == XCD id). Filler if g8%4==3 (512 blocks);
// else GEMM with XCD-local tile map: bx = o*8 + gg%8, by = gg/8.
__global__ __launch_bounds__(256) void gemm_qkv_k(
    const unsigned short* __restrict__ A, const unsigned short* __restrict__ Wt,
    const float* __restrict__ bq, const float* __restrict__ bk,
    const float* __restrict__ bv, unsigned short* __restrict__ Qb,
    unsigned short* __restrict__ Kb, unsigned short* __restrict__ Vb,
    float* __restrict__ wout) {
  __shared__ unsigned short As[128 * 32];
  __shared__ unsigned short Bs[128 * 32];
  const int b = blockIdx.x;
  const int g8 = b >> 3, o = b & 7;

  if ((g8 & 3) == 3) {                 // ---- filler role: chunks [0, Z0_CH)
    const int fb = (g8 >> 2) * 8 + o;  // 0..511
    const unsigned int t0 = fb * 256u + threadIdx.x;   // 0..131071
    f32x4* woutv = (f32x4*)wout;
    for (int it = 0; it < 288; ++it)
      zstore(woutv, (size_t)it * 131072u + t0);
    return;
  }

  const int gg = g8 - (g8 >> 2);       // 0..191 gemm group
  const int row0 = (o * 8 + (gg & 7)) * 128;   // A-band resident per XCD L2
  const int col0 = (gg >> 3) * 128;            // 24 col tiles

  const int tid = threadIdx.x;
  const int lane = tid & 63;
  const int wid = tid >> 6;
  const int wm = wid >> 1, wn = wid & 1;

  f32x4 acc[4][4] = {};
  const int frow = lane & 15;
  const int koff = (lane >> 4) << 3;

  for (int kt = 0; kt < 32; ++kt) {
#pragma unroll
    for (int i = 0; i < 2; ++i) {
      int c = tid + (i << 8);
      int r = c >> 2;
      int kk = (c & 3) << 3;
      GLD16(A + (size_t)(row0 + r) * D_ + (kt << 5) + kk, (char*)As + c * 16);
      GLD16(Wt + (size_t)(col0 + r) * D_ + (kt << 5) + kk, (char*)Bs + c * 16);
    }
    __syncthreads();
    short8 af[4], bfr[4];
#pragma unroll
    for (int mi = 0; mi < 4; ++mi)
      af[mi] = *reinterpret_cast<const short8*>(
          &As[(wm * 64 + mi * 16 + frow) * 32 + koff]);
#pragma unroll
    for (int ni = 0; ni < 4; ++ni)
      bfr[ni] = *reinterpret_cast<const short8*>(
          &Bs[(wn * 64 + ni * 16 + frow) * 32 + koff]);
#pragma unroll
    for (int mi = 0; mi < 4; ++mi)
#pragma unroll
      for (int ni = 0; ni < 4; ++ni)
        acc[mi][ni] = __builtin_amdgcn_mfma_f32_16x16x32_bf16(
            af[mi], bfr[ni], acc[mi][ni], 0, 0, 0);
    __syncthreads();
  }

#pragma unroll
  for (int mi = 0; mi < 4; ++mi) {
#pragma unroll
    for (int ni = 0; ni < 4; ++ni) {
#pragma unroll
      for (int r = 0; r < 4; ++r) {
        int gr = row0 + wm * 64 + mi * 16 + ((lane >> 4) << 2) + r;
        int gc = col0 + wn * 64 + ni * 16 + (lane & 15);
        int z = gc >> 10;                          // block-uniform
        int ci = gc & 1023;
        float bias = (z == 0) ? bq[ci] : (z == 1) ? bk[ci] : bv[ci];
        unsigned short* outp = (z == 0) ? Qb : (z == 1) ? Kb : Vb;
        int bb = gr >> 11, s = gr & (S_ - 1);
        int h = ci >> 6, hd = ci & 63;
        outp[(((size_t)(bb * H_ + h) * S_ + s) << 6) + hd] =
            f2bf(acc[mi][ni][r] + bias);
      }
    }
  }
}

// ---------------- out GEMM (M=8192, N=1024, K=1024), fp32 out --------------
// 768 blocks: filler if g8%3==2 (256 blocks); else 512 GEMM blocks.
__global__ __launch_bounds__(256) void gemm_out_k(
    const unsigned short* __restrict__ A, const unsigned short* __restrict__ Bt,
    const float* __restrict__ bias, float* __restrict__ o_,
    float* __restrict__ wout) {
  __shared__ unsigned short As[128 * 32];
  __shared__ unsigned short Bs[128 * 32];
  const int b = blockIdx.x;
  const int g8 = b >> 3, o = b & 7;

  if (g8 % 3 == 2) {                   // ---- filler role: [Z0_CH, ZA_BASE)
    const int fb = (g8 / 3) * 8 + o;   // 0..255
    const unsigned int t0 = fb * 256u + threadIdx.x;   // 0..65535
    f32x4* woutv = (f32x4*)wout;
    for (int it = 0; it < 256; ++it)
      zstore(woutv, Z0_CH + (size_t)it * 65536u + t0);
    return;
  }

  const int gg = g8 - (g8 + 1) / 3;    // 0..63 gemm group
  const int row0 = (o * 8 + (gg & 7)) * 128;
  const int col0 = (gg >> 3) * 128;

  const int tid = threadIdx.x;
  const int lane = tid & 63;
  const int wid = tid >> 6;
  const int wm = wid >> 1, wn = wid & 1;

  f32x4 acc[4][4] = {};
  const int frow = lane & 15;
  const int koff = (lane >> 4) << 3;

  for (int kt = 0; kt < 32; ++kt) {
#pragma unroll
    for (int i = 0; i < 2; ++i) {
      int c = tid + (i << 8);
      int r = c >> 2;
      int kk = (c & 3) << 3;
      GLD16(A + (size_t)(row0 + r) * D_ + (kt << 5) + kk, (char*)As + c * 16);
      GLD16(Bt + (size_t)(col0 + r) * D_ + (kt << 5) + kk, (char*)Bs + c * 16);
    }
    __syncthreads();
    short8 af[4], bfr[4];
#pragma unroll
    for (int mi = 0; mi < 4; ++mi)
      af[mi] = *reinterpret_cast<const short8*>(
          &As[(wm * 64 + mi * 16 + frow) * 32 + koff]);
#pragma unroll
    for (int ni = 0; ni < 4; ++ni)
      bfr[ni] = *reinterpret_cast<const short8*>(
          &Bs[(wn * 64 + ni * 16 + frow) * 32 + koff]);
#pragma unroll
    for (int mi = 0; mi < 4; ++mi)
#pragma unroll
      for (int ni = 0; ni < 4; ++ni)
        acc[mi][ni] = __builtin_amdgcn_mfma_f32_16x16x32_bf16(
            af[mi], bfr[ni], acc[mi][ni], 0, 0, 0);
    __syncthreads();
  }

#pragma unroll
  for (int mi = 0; mi < 4; ++mi) {
#pragma unroll
    for (int ni = 0; ni < 4; ++ni) {
#pragma unroll
      for (int r = 0; r < 4; ++r) {
        int gr = row0 + wm * 64 + mi * 16 + ((lane >> 4) << 2) + r;
        int gc = col0 + wn * 64 + ni * 16 + (lane & 15);
        o_[(size_t)gr * D_ + gc] = acc[mi][ni][r] + bias[gc];
      }
    }
  }
}

// ---------------- banded attention: one wave per (b,h,q) row ---------------
__global__ __launch_bounds__(256) void attn_k(const unsigned short* __restrict__ Q,
                                              const unsigned short* __restrict__ K,
                                              const unsigned short* __restrict__ V,
                                              float* __restrict__ wout,
                                              unsigned short* __restrict__ attn) {
  int lane = threadIdx.x & 63;
  int wid = threadIdx.x >> 6;
  int row = blockIdx.x * 4 + wid;       // bh*2048 + s
  int s = row & (S_ - 1);
  int bh = row >> 11;                   // b*16 + h
  int b = bh >> 4, h = bh & 15;
  float qd = bf2f(Q[(size_t)row * HD_ + lane]);
  const unsigned short* Kb = K + (size_t)bh * S_ * HD_;
  const unsigned short* Vb = V + (size_t)bh * S_ * HD_;

  float sc[9];
#pragma unroll
  for (int j = 0; j < 9; ++j) {
    int ks = s - WIN_ + j;
    bool ok = (ks >= 0) && (ks < S_);
    float v = ok ? qd * bf2f(Kb[(size_t)ks * HD_ + lane]) : 0.f;
#pragma unroll
    for (int off = 32; off > 0; off >>= 1) v += __shfl_xor(v, off, 64);
    sc[j] = ok ? v * 0.125f : -INFINITY;  // 1/sqrt(64)
  }
  float m = sc[0];
#pragma unroll
  for (int j = 1; j < 9; ++j) m = fmaxf(m, sc[j]);
  float w[9];
  float sum = 0.f;
#pragma unroll
  for (int j = 0; j < 9; ++j) { w[j] = __expf(sc[j] - m); sum += w[j]; }
  float inv = 1.f / sum;
#pragma unroll
  for (int j = 0; j < 9; ++j) w[j] *= inv;  // wave-uniform normalized weights

  float o = 0.f;
#pragma unroll
  for (int j = 0; j < 9; ++j) {
    int ks = s - WIN_ + j;
    if (ks >= 0 && ks < S_) o += w[j] * bf2f(Vb[(size_t)ks * HD_ + lane]);
  }
  attn[((size_t)(b * S_ + s)) * D_ + h * HD_ + lane] = f2bf(o);

  // ---- band chunks (1-3 x 16B), zeros + band values merged ----
  const int lo = s - WIN_;
  const int hiq = (s + WIN_ < S_ - 1) ? (s + WIN_) : (S_ - 1);
  const int f0 = (s > WIN_) ? ((s - WIN_) >> 2) : 0;
  const int f1 = hiq >> 2;
  f32x4* rowp = reinterpret_cast<f32x4*>(wout + (size_t)row * S_);
  if (lane <= f1 - f0) {
    f32x4 v4;
#pragma unroll
    for (int e = 0; e < 4; ++e) {
      int d = ((f0 + lane) << 2) + e - lo;   // band index if in [0,8]
      float val = 0.f;
#pragma unroll
      for (int j = 0; j < 9; ++j)
        if (d == j) val = w[j];
      v4[e] = val;
    }
    __builtin_nontemporal_store(v4, rowp + f0 + lane);
  }

  // ---- zero share: chunks [ZA_BASE, TOTAL_CH) ----
  unsigned int gtid = blockIdx.x * 256u + threadIdx.x;   // [0, 8388608)
#pragma unroll
  for (int k2 = 0; k2 < 2; ++k2) {
    size_t g = ZA_BASE + (size_t)k2 * 8388608u + gtid;
    if (g < TOTAL_CH) zstore((f32x4*)wout, g);
  }
}

// ---------------------------------------------------------------------------
extern "C" void kernel_launch(void* const* d_in, const int* in_sizes, int n_in,
                              void* d_out, int out_size, void* d_ws,
                              size_t ws_size, hipStream_t stream) {
  const float* x = (const float*)d_in[0];
  const float* Wq = (const float*)d_in[1];
  const float* bq = (const float*)d_in[2];
  const float* Wk = (const float*)d_in[3];
  const float* bk = (const float*)d_in[4];
  const float* Wv = (const float*)d_in[5];
  const float* bv = (const float*)d_in[6];
  const float* Wo = (const float*)d_in[7];
  const float* bo = (const float*)d_in[8];
  float* out = (float*)d_out;
  float* wout = out + OUT0_ELEMS;

  char* ws = (char*)d_ws;
  unsigned short* x_bf = (unsigned short*)(ws);                  // 16 MB @ 0
  unsigned short* Wt = (unsigned short*)(ws + (16ull << 20));    //  8 MB @ 16
  unsigned short* Qb = (unsigned short*)(ws + (24ull << 20));    // 16 MB @ 24
  unsigned short* Kb = (unsigned short*)(ws + (40ull << 20));    // 16 MB @ 40
  unsigned short* Vb = (unsigned short*)(ws + (56ull << 20));    // 16 MB @ 56
  unsigned short* attn = (unsigned short*)(ws + (72ull << 20));  // 16 MB @ 72

  xconv_k<<<NROW * D_ / 1024, 256, 0, stream>>>(x, x_bf);
  wconv_k<<<dim3(32, 32, 4), dim3(32, 8), 0, stream>>>(Wq, Wk, Wv, Wo, Wt);
  gemm_qkv_k<<<2048, 256, 0, stream>>>(x_bf, Wt, bq, bk, bv, Qb, Kb, Vb, wout);
  attn_k<<<(B_ * H_ * S_) / 4, 256, 0, stream>>>(Qb, Kb, Vb, wout, attn);
  gemm_out_k<<<768, 256, 0, stream>>>(attn, Wt + (size_t)3 * D_ * D_, bo, out,
                                      wout);
}

// Round 7
// 282.591 us; speedup vs baseline: 1.2146x; 1.2146x over previous
//
#include <hip/hip_runtime.h>

// ---------------------------------------------------------------------------
// SparseMultiHeadAttention (windowed, W=4) forward on MI355X / gfx950
// R7: R3 arrangement (attn_k owns full weights write) + bf16 QKV + fused
//     single QKV GEMM + XCD-aware GEMM tile map.
//   x -> bf16                                  (xconv_k)
//   Wq/Wk/Wv/Wo -> bf16 transposed [N][K]      (wconv_k)
//   QKV = x@[Wq|Wk|Wv]+b, bf16 out             (gemm_qkv_k, 1536 blocks)
//   banded softmax + PV + FULL weights-row
//   write (zeros + band, NT f32x4)             (attn_k)
//   out = attn@Wo + bo, fp32                   (gemm_out_k, 512 blocks)
// ---------------------------------------------------------------------------

typedef __attribute__((ext_vector_type(8))) short short8;
typedef __attribute__((ext_vector_type(4))) float f32x4;

#define B_    4
#define S_    2048
#define D_    1024
#define H_    16
#define HD_   64
#define WIN_  4
#define NROW  (B_ * S_)                           /* 8192 */
#define OUT0_ELEMS  ((size_t)B_ * S_ * D_)        /* 8388608 */

__device__ __forceinline__ unsigned short f2bf(float f) {
  unsigned int u = __float_as_uint(f);
  u += 0x7fffu + ((u >> 16) & 1u);                // round-to-nearest-even
  return (unsigned short)(u >> 16);
}
__device__ __forceinline__ float bf2f(unsigned short u) {
  return __uint_as_float(((unsigned int)u) << 16);
}

// ---------------- fp32 -> bf16 elementwise (x) ------------------------------
__global__ __launch_bounds__(256) void xconv_k(const float* __restrict__ x,
                                               unsigned short* __restrict__ o) {
  int i = blockIdx.x * 256 + threadIdx.x;         // one float4 per thread
  float4 f = reinterpret_cast<const float4*>(x)[i];
  ushort4 u;
  u.x = f2bf(f.x); u.y = f2bf(f.y); u.z = f2bf(f.z); u.w = f2bf(f.w);
  reinterpret_cast<ushort4*>(o)[i] = u;
}

// ---------------- fp32 [K][N] -> bf16 transposed [N][K] (4 weight mats) -----
__global__ __launch_bounds__(256) void wconv_k(const float* __restrict__ W0,
                                               const float* __restrict__ W1,
                                               const float* __restrict__ W2,
                                               const float* __restrict__ W3,
                                               unsigned short* __restrict__ out) {
  __shared__ float t[32][33];
  const float* Ws[4] = {W0, W1, W2, W3};
  const float* W = Ws[blockIdx.z];
  unsigned short* o = out + (size_t)blockIdx.z * D_ * D_;
  int tx = threadIdx.x;                           // 0..31
  int ty = threadIdx.y;                           // 0..7
  int n0 = blockIdx.x * 32, k0 = blockIdx.y * 32;
#pragma unroll
  for (int i = 0; i < 4; ++i)
    t[ty + 8 * i][tx] = W[(size_t)(k0 + ty + 8 * i) * D_ + (n0 + tx)];
  __syncthreads();
#pragma unroll
  for (int i = 0; i < 4; ++i)
    o[(size_t)(n0 + ty + 8 * i) * D_ + (k0 + tx)] = f2bf(t[tx][ty + 8 * i]);
}

#define GLD16(g, l)                                                            \
  __builtin_amdgcn_global_load_lds(                                            \
      (const __attribute__((address_space(1))) unsigned int*)(g),              \
      (__attribute__((address_space(3))) unsigned int*)(l), 16, 0, 0)

// ---------------- fused QKV GEMM (M=8192, N=3072, K=1024), bf16 out --------
// 1536 blocks, XCD map: o=b&7 (XCD), gg=b>>3; row0=(o*8+gg%8)*128 (A panel
// pinned per XCD L2), col0=(gg/8)*128.
__global__ __launch_bounds__(256) void gemm_qkv_k(
    const unsigned short* __restrict__ A, const unsigned short* __restrict__ Wt,
    const float* __restrict__ bq, const float* __restrict__ bk,
    const float* __restrict__ bv, unsigned short* __restrict__ Qb,
    unsigned short* __restrict__ Kb, unsigned short* __restrict__ Vb) {
  __shared__ unsigned short As[128 * 32];
  __shared__ unsigned short Bs[128 * 32];
  const int g = blockIdx.x;
  const int o = g & 7, gg = g >> 3;               // gg in 0..191
  const int row0 = (o * 8 + (gg & 7)) * 128;
  const int col0 = (gg >> 3) * 128;               // 24 col tiles (N=3072)

  const int tid = threadIdx.x;
  const int lane = tid & 63;
  const int wid = tid >> 6;
  const int wm = wid >> 1, wn = wid & 1;

  f32x4 acc[4][4] = {};
  const int frow = lane & 15;
  const int koff = (lane >> 4) << 3;

  for (int kt = 0; kt < 32; ++kt) {
#pragma unroll
    for (int i = 0; i < 2; ++i) {
      int c = tid + (i << 8);
      int r = c >> 2;
      int kk = (c & 3) << 3;
      GLD16(A + (size_t)(row0 + r) * D_ + (kt << 5) + kk, (char*)As + c * 16);
      GLD16(Wt + (size_t)(col0 + r) * D_ + (kt << 5) + kk, (char*)Bs + c * 16);
    }
    __syncthreads();
    short8 af[4], bfr[4];
#pragma unroll
    for (int mi = 0; mi < 4; ++mi)
      af[mi] = *reinterpret_cast<const short8*>(
          &As[(wm * 64 + mi * 16 + frow) * 32 + koff]);
#pragma unroll
    for (int ni = 0; ni < 4; ++ni)
      bfr[ni] = *reinterpret_cast<const short8*>(
          &Bs[(wn * 64 + ni * 16 + frow) * 32 + koff]);
#pragma unroll
    for (int mi = 0; mi < 4; ++mi)
#pragma unroll
      for (int ni = 0; ni < 4; ++ni)
        acc[mi][ni] = __builtin_amdgcn_mfma_f32_16x16x32_bf16(
            af[mi], bfr[ni], acc[mi][ni], 0, 0, 0);
    __syncthreads();
  }

#pragma unroll
  for (int mi = 0; mi < 4; ++mi) {
#pragma unroll
    for (int ni = 0; ni < 4; ++ni) {
#pragma unroll
      for (int r = 0; r < 4; ++r) {
        int gr = row0 + wm * 64 + mi * 16 + ((lane >> 4) << 2) + r;
        int gc = col0 + wn * 64 + ni * 16 + (lane & 15);
        int z = gc >> 10;                          // block-uniform
        int ci = gc & 1023;
        float bias = (z == 0) ? bq[ci] : (z == 1) ? bk[ci] : bv[ci];
        unsigned short* outp = (z == 0) ? Qb : (z == 1) ? Kb : Vb;
        int bb = gr >> 11, s = gr & (S_ - 1);
        int h = ci >> 6, hd = ci & 63;
        outp[(((size_t)(bb * H_ + h) * S_ + s) << 6) + hd] =
            f2bf(acc[mi][ni][r] + bias);
      }
    }
  }
}

// ---------------- out GEMM (M=8192, N=1024, K=1024), fp32 out --------------
// 512 blocks, same XCD map (64 row x 8 col tiles).
__global__ __launch_bounds__(256) void gemm_out_k(
    const unsigned short* __restrict__ A, const unsigned short* __restrict__ Bt,
    const float* __restrict__ bias, float* __restrict__ o_) {
  __shared__ unsigned short As[128 * 32];
  __shared__ unsigned short Bs[128 * 32];
  const int g = blockIdx.x;
  const int o = g & 7, gg = g >> 3;               // gg in 0..63
  const int row0 = (o * 8 + (gg & 7)) * 128;
  const int col0 = (gg >> 3) * 128;

  const int tid = threadIdx.x;
  const int lane = tid & 63;
  const int wid = tid >> 6;
  const int wm = wid >> 1, wn = wid & 1;

  f32x4 acc[4][4] = {};
  const int frow = lane & 15;
  const int koff = (lane >> 4) << 3;

  for (int kt = 0; kt < 32; ++kt) {
#pragma unroll
    for (int i = 0; i < 2; ++i) {
      int c = tid + (i << 8);
      int r = c >> 2;
      int kk = (c & 3) << 3;
      GLD16(A + (size_t)(row0 + r) * D_ + (kt << 5) + kk, (char*)As + c * 16);
      GLD16(Bt + (size_t)(col0 + r) * D_ + (kt << 5) + kk, (char*)Bs + c * 16);
    }
    __syncthreads();
    short8 af[4], bfr[4];
#pragma unroll
    for (int mi = 0; mi < 4; ++mi)
      af[mi] = *reinterpret_cast<const short8*>(
          &As[(wm * 64 + mi * 16 + frow) * 32 + koff]);
#pragma unroll
    for (int ni = 0; ni < 4; ++ni)
      bfr[ni] = *reinterpret_cast<const short8*>(
          &Bs[(wn * 64 + ni * 16 + frow) * 32 + koff]);
#pragma unroll
    for (int mi = 0; mi < 4; ++mi)
#pragma unroll
      for (int ni = 0; ni < 4; ++ni)
        acc[mi][ni] = __builtin_amdgcn_mfma_f32_16x16x32_bf16(
            af[mi], bfr[ni], acc[mi][ni], 0, 0, 0);
    __syncthreads();
  }

#pragma unroll
  for (int mi = 0; mi < 4; ++mi) {
#pragma unroll
    for (int ni = 0; ni < 4; ++ni) {
#pragma unroll
      for (int r = 0; r < 4; ++r) {
        int gr = row0 + wm * 64 + mi * 16 + ((lane >> 4) << 2) + r;
        int gc = col0 + wn * 64 + ni * 16 + (lane & 15);
        o_[(size_t)gr * D_ + gc] = acc[mi][ni][r] + bias[gc];
      }
    }
  }
}

// ---------------- banded attention + full weights-row write ----------------
// one wave per (b,h,q) row; 64 lanes write the entire 2048-float row
// (zeros + 9 band values) as 512 coalesced NT f32x4 stores.
__global__ __launch_bounds__(256) void attn_k(const unsigned short* __restrict__ Q,
                                              const unsigned short* __restrict__ K,
                                              const unsigned short* __restrict__ V,
                                              float* __restrict__ wout,
                                              unsigned short* __restrict__ attn) {
  int lane = threadIdx.x & 63;
  int wid = threadIdx.x >> 6;
  int row = blockIdx.x * 4 + wid;       // bh*2048 + s
  int s = row & (S_ - 1);
  int bh = row >> 11;                   // b*16 + h
  int b = bh >> 4, h = bh & 15;
  float qd = bf2f(Q[(size_t)row * HD_ + lane]);
  const unsigned short* Kb = K + (size_t)bh * S_ * HD_;
  const unsigned short* Vb = V + (size_t)bh * S_ * HD_;

  float sc[9];
#pragma unroll
  for (int j = 0; j < 9; ++j) {
    int ks = s - WIN_ + j;
    bool ok = (ks >= 0) && (ks < S_);
    float v = ok ? qd * bf2f(Kb[(size_t)ks * HD_ + lane]) : 0.f;
#pragma unroll
    for (int off = 32; off > 0; off >>= 1) v += __shfl_xor(v, off, 64);
    sc[j] = ok ? v * 0.125f : -INFINITY;  // 1/sqrt(64)
  }
  float m = sc[0];
#pragma unroll
  for (int j = 1; j < 9; ++j) m = fmaxf(m, sc[j]);
  float w[9];
  float sum = 0.f;
#pragma unroll
  for (int j = 0; j < 9; ++j) { w[j] = __expf(sc[j] - m); sum += w[j]; }
  float inv = 1.f / sum;
#pragma unroll
  for (int j = 0; j < 9; ++j) w[j] *= inv;  // wave-uniform normalized weights

  float o = 0.f;
#pragma unroll
  for (int j = 0; j < 9; ++j) {
    int ks = s - WIN_ + j;
    if (ks >= 0 && ks < S_) o += w[j] * bf2f(Vb[(size_t)ks * HD_ + lane]);
  }
  attn[((size_t)(b * S_ + s)) * D_ + h * HD_ + lane] = f2bf(o);

  // ---- full weights row: 8 NT f32x4 per lane, band select-merged ----
  f32x4* rowp = reinterpret_cast<f32x4*>(wout + (size_t)row * S_);
  const int lo = s - WIN_;              // first band col (may be <0)
  const int hi = s + WIN_;              // last band col (may be >=S_)
#pragma unroll
  for (int i = 0; i < 8; ++i) {
    int f = lane + (i << 6);            // f32x4 chunk 0..511
    int c0 = f << 2;                    // first col of chunk
    f32x4 v4 = {0.f, 0.f, 0.f, 0.f};
    if (c0 + 3 >= lo && c0 <= hi) {     // chunk overlaps band (<=3 lanes)
#pragma unroll
      for (int e = 0; e < 4; ++e) {
        int d = c0 + e - lo;            // band index if in [0,8]
        float val = 0.f;
#pragma unroll
        for (int j = 0; j < 9; ++j)
          if (d == j) val = w[j];       // static-index select chain
        v4[e] = val;
      }
    }
    __builtin_nontemporal_store(v4, rowp + f);
  }
}

// ---------------------------------------------------------------------------
extern "C" void kernel_launch(void* const* d_in, const int* in_sizes, int n_in,
                              void* d_out, int out_size, void* d_ws,
                              size_t ws_size, hipStream_t stream) {
  const float* x = (const float*)d_in[0];
  const float* Wq = (const float*)d_in[1];
  const float* bq = (const float*)d_in[2];
  const float* Wk = (const float*)d_in[3];
  const float* bk = (const float*)d_in[4];
  const float* Wv = (const float*)d_in[5];
  const float* bv = (const float*)d_in[6];
  const float* Wo = (const float*)d_in[7];
  const float* bo = (const float*)d_in[8];
  float* out = (float*)d_out;
  float* wout = out + OUT0_ELEMS;

  char* ws = (char*)d_ws;
  unsigned short* x_bf = (unsigned short*)(ws);                  // 16 MB @ 0
  unsigned short* Wt = (unsigned short*)(ws + (16ull << 20));    //  8 MB @ 16
  unsigned short* Qb = (unsigned short*)(ws + (24ull << 20));    // 16 MB @ 24
  unsigned short* Kb = (unsigned short*)(ws + (40ull << 20));    // 16 MB @ 40
  unsigned short* Vb = (unsigned short*)(ws + (56ull << 20));    // 16 MB @ 56
  unsigned short* attn = (unsigned short*)(ws + (72ull << 20));  // 16 MB @ 72

  xconv_k<<<NROW * D_ / 1024, 256, 0, stream>>>(x, x_bf);
  wconv_k<<<dim3(32, 32, 4), dim3(32, 8), 0, stream>>>(Wq, Wk, Wv, Wo, Wt);
  gemm_qkv_k<<<1536, 256, 0, stream>>>(x_bf, Wt, bq, bk, bv, Qb, Kb, Vb);
  attn_k<<<(B_ * H_ * S_) / 4, 256, 0, stream>>>(Qb, Kb, Vb, wout, attn);
  gemm_out_k<<<512, 256, 0, stream>>>(attn, Wt + (size_t)3 * D_ * D_, bo, out);
}